// Round 9
// baseline (674.237 us; speedup 1.0000x reference)
//
#include <hip/hip_runtime.h>

#define N_NODES 100000
#define N_EDGES 1600000
#define DIM 5
#define HID 64
#define N_LAYERS 3
#define SCAN_BLK 256
#define NBLK ((N_NODES + SCAN_BLK - 1) / SCAN_BLK)   // 391
#define CNT_STRIDE 16   // pad: one counter per 64B line (atomic line-serialization probe)

// ================= CSR build =================

__global__ __launch_bounds__(256) void hist_kernel(
    const int* __restrict__ ei, int* __restrict__ cnt, int* __restrict__ rank)
{
    int e = blockIdx.x * blockDim.x + threadIdx.x;
    if (e >= N_EDGES) return;
    int dst = ei[N_EDGES + e];
    rank[e] = atomicAdd(&cnt[(long)dst * CNT_STRIDE], 1);
}

__global__ __launch_bounds__(SCAN_BLK) void scan_part_kernel(
    const int* __restrict__ cnt, int* __restrict__ blk_sum)
{
    __shared__ int s[SCAN_BLK];
    int t = threadIdx.x;
    int i = blockIdx.x * SCAN_BLK + t;
    s[t] = (i < N_NODES) ? cnt[(long)i * CNT_STRIDE] : 0;
    __syncthreads();
    for (int off = SCAN_BLK / 2; off > 0; off >>= 1) {
        if (t < off) s[t] += s[t + off];
        __syncthreads();
    }
    if (t == 0) blk_sum[blockIdx.x] = s[0];
}

__global__ __launch_bounds__(512) void scan_blk_kernel(
    const int* __restrict__ blk_sum, int* __restrict__ blk_pref)
{
    __shared__ int s[512];
    int t = threadIdx.x;
    int v = (t < NBLK) ? blk_sum[t] : 0;
    s[t] = v;
    __syncthreads();
    for (int off = 1; off < 512; off <<= 1) {
        int a = (t >= off) ? s[t - off] : 0;
        __syncthreads();
        s[t] += a;
        __syncthreads();
    }
    if (t < NBLK) blk_pref[t] = s[t] - v;   // exclusive prefix
}

__global__ __launch_bounds__(SCAN_BLK) void scan_add_kernel(
    const int* __restrict__ cnt, const int* __restrict__ blk_pref,
    int* __restrict__ row_ptr)
{
    __shared__ int s[SCAN_BLK];
    int t = threadIdx.x;
    int i = blockIdx.x * SCAN_BLK + t;
    int c = (i < N_NODES) ? cnt[(long)i * CNT_STRIDE] : 0;
    s[t] = c;
    __syncthreads();
    for (int off = 1; off < SCAN_BLK; off <<= 1) {
        int a = (t >= off) ? s[t - off] : 0;
        __syncthreads();
        s[t] += a;
        __syncthreads();
    }
    if (i < N_NODES) row_ptr[i] = blk_pref[blockIdx.x] + s[t] - c;
    if (i == 0) row_ptr[N_NODES] = N_EDGES;
}

// writes only sorted src (dst implicit via row_ptr segments)
__global__ __launch_bounds__(256) void scatter_src_kernel(
    const int* __restrict__ ei, const int* __restrict__ rank,
    const int* __restrict__ row_ptr, int* __restrict__ ssrc)
{
    int e = blockIdx.x * blockDim.x + threadIdx.x;
    if (e >= N_EDGES) return;
    int src = ei[e];
    int dst = ei[N_EDGES + e];
    ssrc[row_ptr[dst] + rank[e]] = src;
}

// ================= fused per-layer kernel =================
// Thread-per-node: aggr = sum over incoming edges of msgMLP([x_v, x_src]),
// then upd = relu([x_v, aggr]@U1+bu1)@U2+bu2 ; x' = upd + x_v ; optional readout.
// Note: reference adds b2 per edge -> agg += deg * b2.
template <bool FINAL>
__global__ __launch_bounds__(256) void fused_layer_kernel(
    const float* __restrict__ x,
    const int* __restrict__ ssrc,
    const int* __restrict__ row_ptr,
    const float* __restrict__ W1, const float* __restrict__ b1,
    const float* __restrict__ W2, const float* __restrict__ b2,
    const float* __restrict__ U1, const float* __restrict__ bu1,
    const float* __restrict__ U2, const float* __restrict__ bu2,
    const float* __restrict__ Wr, const float* __restrict__ br,
    float* __restrict__ xout)
{
    int v = blockIdx.x * blockDim.x + threadIdx.x;
    if (v >= N_NODES) return;

    float xv[DIM];
#pragma unroll
    for (int d = 0; d < DIM; ++d) xv[d] = x[(long)v * DIM + d];

    int s = row_ptr[v], epos = row_ptr[v + 1];
    int deg = epos - s;

    float agg[DIM] = {0.f, 0.f, 0.f, 0.f, 0.f};
    for (int e = s; e < epos; ++e) {
        int src = ssrc[e];
        float in[10];
#pragma unroll
        for (int d = 0; d < DIM; ++d) in[d] = xv[d];
        const float* xs = x + (long)src * DIM;
#pragma unroll
        for (int d = 0; d < DIM; ++d) in[DIM + d] = xs[d];

#pragma unroll 4
        for (int h = 0; h < HID; ++h) {
            float acc = b1[h];
#pragma unroll
            for (int d = 0; d < 10; ++d) acc = fmaf(in[d], W1[d * HID + h], acc);
            acc = fmaxf(acc, 0.0f);
#pragma unroll
            for (int j = 0; j < DIM; ++j) agg[j] = fmaf(acc, W2[h * DIM + j], agg[j]);
        }
    }
    float degf = (float)deg;
#pragma unroll
    for (int j = 0; j < DIM; ++j) agg[j] = fmaf(degf, b2[j], agg[j]);

    // update MLP
    float in2[10];
#pragma unroll
    for (int d = 0; d < DIM; ++d) in2[d] = xv[d];
#pragma unroll
    for (int d = 0; d < DIM; ++d) in2[DIM + d] = agg[d];

    float upd[DIM];
#pragma unroll
    for (int j = 0; j < DIM; ++j) upd[j] = bu2[j];

#pragma unroll 4
    for (int h = 0; h < HID; ++h) {
        float acc = bu1[h];
#pragma unroll
        for (int d = 0; d < 10; ++d) acc = fmaf(in2[d], U1[d * HID + h], acc);
        acc = fmaxf(acc, 0.0f);
#pragma unroll
        for (int j = 0; j < DIM; ++j) upd[j] = fmaf(acc, U2[h * DIM + j], upd[j]);
    }

    float xn[DIM];
#pragma unroll
    for (int j = 0; j < DIM; ++j) xn[j] = upd[j] + xv[j];

    if (FINAL) {
#pragma unroll
        for (int j = 0; j < DIM; ++j) {
            float o = br[j];
#pragma unroll
            for (int d = 0; d < DIM; ++d) o = fmaf(xn[d], Wr[d * DIM + j], o);
            xout[(long)v * DIM + j] = o;
        }
    } else {
#pragma unroll
        for (int j = 0; j < DIM; ++j) xout[(long)v * DIM + j] = xn[j];
    }
}

// ================= fallback (round-3 atomic path) =================

__global__ __launch_bounds__(256) void edge_msg_kernel(
    const float* __restrict__ x, const int* __restrict__ ei,
    const float* __restrict__ W1, const float* __restrict__ b1,
    const float* __restrict__ W2, const float* __restrict__ b2,
    float* __restrict__ aggr)
{
    int e = blockIdx.x * blockDim.x + threadIdx.x;
    if (e >= N_EDGES) return;
    int src = ei[e];
    int dst = ei[N_EDGES + e];
    float in[10];
    const float* xi = x + (long)dst * DIM;
    const float* xj = x + (long)src * DIM;
#pragma unroll
    for (int d = 0; d < DIM; ++d) in[d] = xi[d];
#pragma unroll
    for (int d = 0; d < DIM; ++d) in[DIM + d] = xj[d];
    float msg[DIM];
#pragma unroll
    for (int j = 0; j < DIM; ++j) msg[j] = b2[j];
#pragma unroll 4
    for (int h = 0; h < HID; ++h) {
        float acc = b1[h];
#pragma unroll
        for (int d = 0; d < 10; ++d) acc = fmaf(in[d], W1[d * HID + h], acc);
        acc = fmaxf(acc, 0.0f);
#pragma unroll
        for (int j = 0; j < DIM; ++j) msg[j] = fmaf(acc, W2[h * DIM + j], msg[j]);
    }
    float* ap = aggr + (long)dst * DIM;
#pragma unroll
    for (int j = 0; j < DIM; ++j) atomicAdd(ap + j, msg[j]);
}

template <bool FINAL>
__global__ __launch_bounds__(256) void node_upd_kernel(
    const float* __restrict__ x, const float* __restrict__ aggr,
    const float* __restrict__ U1, const float* __restrict__ bu1,
    const float* __restrict__ U2, const float* __restrict__ bu2,
    const float* __restrict__ Wr, const float* __restrict__ br,
    float* __restrict__ xout)
{
    int v = blockIdx.x * blockDim.x + threadIdx.x;
    if (v >= N_NODES) return;
    float in[10];
#pragma unroll
    for (int d = 0; d < DIM; ++d) in[d] = x[(long)v * DIM + d];
#pragma unroll
    for (int d = 0; d < DIM; ++d) in[DIM + d] = aggr[(long)v * DIM + d];
    float upd[DIM];
#pragma unroll
    for (int j = 0; j < DIM; ++j) upd[j] = bu2[j];
#pragma unroll 4
    for (int h = 0; h < HID; ++h) {
        float acc = bu1[h];
#pragma unroll
        for (int d = 0; d < 10; ++d) acc = fmaf(in[d], U1[d * HID + h], acc);
        acc = fmaxf(acc, 0.0f);
#pragma unroll
        for (int j = 0; j < DIM; ++j) upd[j] = fmaf(acc, U2[h * DIM + j], upd[j]);
    }
    float xn[DIM];
#pragma unroll
    for (int j = 0; j < DIM; ++j) xn[j] = upd[j] + in[j];
    if (FINAL) {
#pragma unroll
        for (int j = 0; j < DIM; ++j) {
            float o = br[j];
#pragma unroll
            for (int d = 0; d < DIM; ++d) o = fmaf(xn[d], Wr[d * DIM + j], o);
            xout[(long)v * DIM + j] = o;
        }
    } else {
#pragma unroll
        for (int j = 0; j < DIM; ++j) xout[(long)v * DIM + j] = xn[j];
    }
}

// ================= launch =================

static inline size_t alignup(size_t x) { return (x + 255) & ~(size_t)255; }

extern "C" void kernel_launch(void* const* d_in, const int* in_sizes, int n_in,
                              void* d_out, int out_size, void* d_ws, size_t ws_size,
                              hipStream_t stream) {
    const float* x   = (const float*)d_in[0];
    const int*   ei  = (const int*)d_in[1];
    const float* W1  = (const float*)d_in[2];
    const float* b1  = (const float*)d_in[3];
    const float* W2  = (const float*)d_in[4];
    const float* b2  = (const float*)d_in[5];
    const float* U1  = (const float*)d_in[6];
    const float* bu1 = (const float*)d_in[7];
    const float* U2  = (const float*)d_in[8];
    const float* bu2 = (const float*)d_in[9];
    const float* Wr  = (const float*)d_in[10];
    const float* br  = (const float*)d_in[11];
    float* out = (float*)d_out;

    char* ws = (char*)d_ws;

    // workspace layout
    size_t o_cnt  = 0;                                                     // padded counters
    size_t o_row  = alignup(o_cnt + (size_t)N_NODES * CNT_STRIDE * 4);     // 6.4 MB
    size_t o_bsum = alignup(o_row + (size_t)(N_NODES + 1) * 4);
    size_t o_bpre = alignup(o_bsum + (size_t)NBLK * 4);
    size_t o_ssrc = alignup(o_bpre + (size_t)NBLK * 4);
    size_t o_rank = alignup(o_ssrc + (size_t)N_EDGES * 4);
    size_t o_xA   = alignup(o_rank + (size_t)N_EDGES * 4);
    size_t o_xB   = alignup(o_xA + (size_t)N_NODES * DIM * 4);
    size_t needed = alignup(o_xB + (size_t)N_NODES * DIM * 4);

    dim3 blk(256);
    dim3 eg((N_EDGES + 255) / 256);
    dim3 ng((N_NODES + 255) / 256);

    if (ws_size < needed) {
        // fallback: atomic scatter path (proven correct)
        size_t nbytes = (size_t)N_NODES * DIM * sizeof(float);
        float* aggr = (float*)ws;
        float* xA   = (float*)(ws + nbytes);
        float* xB   = (float*)(ws + 2 * nbytes);
        const float* xcur = x;
        for (int l = 0; l < N_LAYERS; ++l) {
            hipMemsetAsync(aggr, 0, nbytes, stream);
            edge_msg_kernel<<<eg, blk, 0, stream>>>(
                xcur, ei, W1 + l * 10 * HID, b1 + l * HID,
                W2 + l * HID * DIM, b2 + l * DIM, aggr);
            if (l < N_LAYERS - 1) {
                float* xn = (l == 0) ? xA : xB;
                node_upd_kernel<false><<<ng, blk, 0, stream>>>(
                    xcur, aggr, U1 + l * 10 * HID, bu1 + l * HID,
                    U2 + l * HID * DIM, bu2 + l * DIM, Wr, br, xn);
                xcur = xn;
            } else {
                node_upd_kernel<true><<<ng, blk, 0, stream>>>(
                    xcur, aggr, U1 + l * 10 * HID, bu1 + l * HID,
                    U2 + l * HID * DIM, bu2 + l * DIM, Wr, br, out);
            }
        }
        return;
    }

    int* cnt      = (int*)(ws + o_cnt);
    int* row_ptr  = (int*)(ws + o_row);
    int* blk_sum  = (int*)(ws + o_bsum);
    int* blk_pref = (int*)(ws + o_bpre);
    int* ssrc     = (int*)(ws + o_ssrc);
    int* rank     = (int*)(ws + o_rank);
    float* xA     = (float*)(ws + o_xA);
    float* xB     = (float*)(ws + o_xB);

    // ---- CSR build (once per call; reused by all 3 layers) ----
    hipMemsetAsync(cnt, 0, (size_t)N_NODES * CNT_STRIDE * 4, stream);
    hist_kernel<<<eg, blk, 0, stream>>>(ei, cnt, rank);
    scan_part_kernel<<<NBLK, SCAN_BLK, 0, stream>>>(cnt, blk_sum);
    scan_blk_kernel<<<1, 512, 0, stream>>>(blk_sum, blk_pref);
    scan_add_kernel<<<NBLK, SCAN_BLK, 0, stream>>>(cnt, blk_pref, row_ptr);
    scatter_src_kernel<<<eg, blk, 0, stream>>>(ei, rank, row_ptr, ssrc);

    // ---- layers (fused edge-MLP + gather + update) ----
    const float* xcur = x;
    for (int l = 0; l < N_LAYERS; ++l) {
        const float* W1l = W1 + l * 10 * HID;
        const float* b1l = b1 + l * HID;
        const float* W2l = W2 + l * HID * DIM;
        const float* b2l = b2 + l * DIM;
        const float* U1l = U1 + l * 10 * HID;
        const float* bu1l = bu1 + l * HID;
        const float* U2l = U2 + l * HID * DIM;
        const float* bu2l = bu2 + l * DIM;
        if (l < N_LAYERS - 1) {
            float* xn = (l == 0) ? xA : xB;
            fused_layer_kernel<false><<<ng, blk, 0, stream>>>(
                xcur, ssrc, row_ptr, W1l, b1l, W2l, b2l,
                U1l, bu1l, U2l, bu2l, Wr, br, xn);
            xcur = xn;
        } else {
            fused_layer_kernel<true><<<ng, blk, 0, stream>>>(
                xcur, ssrc, row_ptr, W1l, b1l, W2l, b2l,
                U1l, bu1l, U2l, bu2l, Wr, br, out);
        }
    }
}

// Round 10
// 387.320 us; speedup vs baseline: 1.7408x; 1.7408x over previous
//
#include <hip/hip_runtime.h>

#define N_NODES 100000
#define N_EDGES 1600000
#define DIM 5
#define HID 64
#define N_LAYERS 3
#define SCAN_BLK 256
#define NBLK ((N_NODES + SCAN_BLK - 1) / SCAN_BLK)   // 391
#define CNT_STRIDE 16   // one counter per 64B line (atomic line-serialization probe)

// ================= CSR build =================

__global__ __launch_bounds__(256) void hist_kernel(
    const int* __restrict__ ei, int* __restrict__ cnt, int* __restrict__ rank)
{
    int e = blockIdx.x * blockDim.x + threadIdx.x;
    if (e >= N_EDGES) return;
    int dst = ei[N_EDGES + e];
    rank[e] = atomicAdd(&cnt[(long)dst * CNT_STRIDE], 1);
}

__global__ __launch_bounds__(SCAN_BLK) void scan_part_kernel(
    const int* __restrict__ cnt, int* __restrict__ blk_sum)
{
    __shared__ int s[SCAN_BLK];
    int t = threadIdx.x;
    int i = blockIdx.x * SCAN_BLK + t;
    s[t] = (i < N_NODES) ? cnt[(long)i * CNT_STRIDE] : 0;
    __syncthreads();
    for (int off = SCAN_BLK / 2; off > 0; off >>= 1) {
        if (t < off) s[t] += s[t + off];
        __syncthreads();
    }
    if (t == 0) blk_sum[blockIdx.x] = s[0];
}

__global__ __launch_bounds__(512) void scan_blk_kernel(
    const int* __restrict__ blk_sum, int* __restrict__ blk_pref)
{
    __shared__ int s[512];
    int t = threadIdx.x;
    int v = (t < NBLK) ? blk_sum[t] : 0;
    s[t] = v;
    __syncthreads();
    for (int off = 1; off < 512; off <<= 1) {
        int a = (t >= off) ? s[t - off] : 0;
        __syncthreads();
        s[t] += a;
        __syncthreads();
    }
    if (t < NBLK) blk_pref[t] = s[t] - v;   // exclusive prefix
}

__global__ __launch_bounds__(SCAN_BLK) void scan_add_kernel(
    const int* __restrict__ cnt, const int* __restrict__ blk_pref,
    int* __restrict__ row_ptr)
{
    __shared__ int s[SCAN_BLK];
    int t = threadIdx.x;
    int i = blockIdx.x * SCAN_BLK + t;
    int c = (i < N_NODES) ? cnt[(long)i * CNT_STRIDE] : 0;
    s[t] = c;
    __syncthreads();
    for (int off = 1; off < SCAN_BLK; off <<= 1) {
        int a = (t >= off) ? s[t - off] : 0;
        __syncthreads();
        s[t] += a;
        __syncthreads();
    }
    if (i < N_NODES) row_ptr[i] = blk_pref[blockIdx.x] + s[t] - c;
    if (i == 0) row_ptr[N_NODES] = N_EDGES;
}

// write one int2 {src,dst} per edge at its sorted position (8B random write)
__global__ __launch_bounds__(256) void scatter_pair_kernel(
    const int* __restrict__ ei, const int* __restrict__ rank,
    const int* __restrict__ row_ptr, int2* __restrict__ spair)
{
    int e = blockIdx.x * blockDim.x + threadIdx.x;
    if (e >= N_EDGES) return;
    int src = ei[e];
    int dst = ei[N_EDGES + e];
    spair[row_ptr[dst] + rank[e]] = make_int2(src, dst);
}

// ================= per-layer kernels (atomic-free) =================

// msg = relu([x_dst, x_src] @ W1 + b1) @ W2 + b2, written at sorted position
__global__ __launch_bounds__(256) void edge_msg_sorted_kernel(
    const float* __restrict__ x,
    const int2* __restrict__ spair,
    const float* __restrict__ W1, const float* __restrict__ b1,
    const float* __restrict__ W2, const float* __restrict__ b2,
    float* __restrict__ msg_buf)
{
    int e = blockIdx.x * blockDim.x + threadIdx.x;
    if (e >= N_EDGES) return;
    int2 p = spair[e];          // p.x = src, p.y = dst

    float in[10];
    const float* xi = x + (long)p.y * DIM;
    const float* xj = x + (long)p.x * DIM;
#pragma unroll
    for (int d = 0; d < DIM; ++d) in[d] = xi[d];
#pragma unroll
    for (int d = 0; d < DIM; ++d) in[DIM + d] = xj[d];

    float msg[DIM];
#pragma unroll
    for (int j = 0; j < DIM; ++j) msg[j] = b2[j];

#pragma unroll 8
    for (int h = 0; h < HID; ++h) {
        float acc = b1[h];
#pragma unroll
        for (int d = 0; d < 10; ++d) acc = fmaf(in[d], W1[d * HID + h], acc);
        acc = fmaxf(acc, 0.0f);
#pragma unroll
        for (int j = 0; j < DIM; ++j) msg[j] = fmaf(acc, W2[h * DIM + j], msg[j]);
    }

    float* mp = msg_buf + (long)e * DIM;
#pragma unroll
    for (int j = 0; j < DIM; ++j) mp[j] = msg[j];
}

// aggr[v] = sum of msg segment; upd = relu([x,aggr]@U1+bu1)@U2+bu2; x'=upd+x
// FINAL: out = x' @ Wr + br
template <bool FINAL>
__global__ __launch_bounds__(256) void node_gather_update_kernel(
    const float* __restrict__ x,
    const float* __restrict__ msg_buf,
    const int* __restrict__ row_ptr,
    const float* __restrict__ U1, const float* __restrict__ bu1,
    const float* __restrict__ U2, const float* __restrict__ bu2,
    const float* __restrict__ Wr, const float* __restrict__ br,
    float* __restrict__ xout)
{
    int v = blockIdx.x * blockDim.x + threadIdx.x;
    if (v >= N_NODES) return;

    float in[10];
#pragma unroll
    for (int d = 0; d < DIM; ++d) in[d] = x[(long)v * DIM + d];

    float agg[DIM] = {0.f, 0.f, 0.f, 0.f, 0.f};
    int s = row_ptr[v], epos = row_ptr[v + 1];
    for (int e = s; e < epos; ++e) {
        const float* mp = msg_buf + (long)e * DIM;
#pragma unroll
        for (int j = 0; j < DIM; ++j) agg[j] += mp[j];
    }
#pragma unroll
    for (int d = 0; d < DIM; ++d) in[DIM + d] = agg[d];

    float upd[DIM];
#pragma unroll
    for (int j = 0; j < DIM; ++j) upd[j] = bu2[j];

#pragma unroll 8
    for (int h = 0; h < HID; ++h) {
        float acc = bu1[h];
#pragma unroll
        for (int d = 0; d < 10; ++d) acc = fmaf(in[d], U1[d * HID + h], acc);
        acc = fmaxf(acc, 0.0f);
#pragma unroll
        for (int j = 0; j < DIM; ++j) upd[j] = fmaf(acc, U2[h * DIM + j], upd[j]);
    }

    float xn[DIM];
#pragma unroll
    for (int j = 0; j < DIM; ++j) xn[j] = upd[j] + in[j];

    if (FINAL) {
#pragma unroll
        for (int j = 0; j < DIM; ++j) {
            float o = br[j];
#pragma unroll
            for (int d = 0; d < DIM; ++d) o = fmaf(xn[d], Wr[d * DIM + j], o);
            xout[(long)v * DIM + j] = o;
        }
    } else {
#pragma unroll
        for (int j = 0; j < DIM; ++j) xout[(long)v * DIM + j] = xn[j];
    }
}

// ================= fallback (round-3 atomic path) =================

__global__ __launch_bounds__(256) void edge_msg_kernel(
    const float* __restrict__ x, const int* __restrict__ ei,
    const float* __restrict__ W1, const float* __restrict__ b1,
    const float* __restrict__ W2, const float* __restrict__ b2,
    float* __restrict__ aggr)
{
    int e = blockIdx.x * blockDim.x + threadIdx.x;
    if (e >= N_EDGES) return;
    int src = ei[e];
    int dst = ei[N_EDGES + e];
    float in[10];
    const float* xi = x + (long)dst * DIM;
    const float* xj = x + (long)src * DIM;
#pragma unroll
    for (int d = 0; d < DIM; ++d) in[d] = xi[d];
#pragma unroll
    for (int d = 0; d < DIM; ++d) in[DIM + d] = xj[d];
    float msg[DIM];
#pragma unroll
    for (int j = 0; j < DIM; ++j) msg[j] = b2[j];
#pragma unroll 8
    for (int h = 0; h < HID; ++h) {
        float acc = b1[h];
#pragma unroll
        for (int d = 0; d < 10; ++d) acc = fmaf(in[d], W1[d * HID + h], acc);
        acc = fmaxf(acc, 0.0f);
#pragma unroll
        for (int j = 0; j < DIM; ++j) msg[j] = fmaf(acc, W2[h * DIM + j], msg[j]);
    }
    float* ap = aggr + (long)dst * DIM;
#pragma unroll
    for (int j = 0; j < DIM; ++j) atomicAdd(ap + j, msg[j]);
}

template <bool FINAL>
__global__ __launch_bounds__(256) void node_upd_kernel(
    const float* __restrict__ x, const float* __restrict__ aggr,
    const float* __restrict__ U1, const float* __restrict__ bu1,
    const float* __restrict__ U2, const float* __restrict__ bu2,
    const float* __restrict__ Wr, const float* __restrict__ br,
    float* __restrict__ xout)
{
    int v = blockIdx.x * blockDim.x + threadIdx.x;
    if (v >= N_NODES) return;
    float in[10];
#pragma unroll
    for (int d = 0; d < DIM; ++d) in[d] = x[(long)v * DIM + d];
#pragma unroll
    for (int d = 0; d < DIM; ++d) in[DIM + d] = aggr[(long)v * DIM + d];
    float upd[DIM];
#pragma unroll
    for (int j = 0; j < DIM; ++j) upd[j] = bu2[j];
#pragma unroll 8
    for (int h = 0; h < HID; ++h) {
        float acc = bu1[h];
#pragma unroll
        for (int d = 0; d < 10; ++d) acc = fmaf(in[d], U1[d * HID + h], acc);
        acc = fmaxf(acc, 0.0f);
#pragma unroll
        for (int j = 0; j < DIM; ++j) upd[j] = fmaf(acc, U2[h * DIM + j], upd[j]);
    }
    float xn[DIM];
#pragma unroll
    for (int j = 0; j < DIM; ++j) xn[j] = upd[j] + in[j];
    if (FINAL) {
#pragma unroll
        for (int j = 0; j < DIM; ++j) {
            float o = br[j];
#pragma unroll
            for (int d = 0; d < DIM; ++d) o = fmaf(xn[d], Wr[d * DIM + j], o);
            xout[(long)v * DIM + j] = o;
        }
    } else {
#pragma unroll
        for (int j = 0; j < DIM; ++j) xout[(long)v * DIM + j] = xn[j];
    }
}

// ================= launch =================

static inline size_t alignup(size_t x) { return (x + 255) & ~(size_t)255; }

extern "C" void kernel_launch(void* const* d_in, const int* in_sizes, int n_in,
                              void* d_out, int out_size, void* d_ws, size_t ws_size,
                              hipStream_t stream) {
    const float* x   = (const float*)d_in[0];
    const int*   ei  = (const int*)d_in[1];
    const float* W1  = (const float*)d_in[2];
    const float* b1  = (const float*)d_in[3];
    const float* W2  = (const float*)d_in[4];
    const float* b2  = (const float*)d_in[5];
    const float* U1  = (const float*)d_in[6];
    const float* bu1 = (const float*)d_in[7];
    const float* U2  = (const float*)d_in[8];
    const float* bu2 = (const float*)d_in[9];
    const float* Wr  = (const float*)d_in[10];
    const float* br  = (const float*)d_in[11];
    float* out = (float*)d_out;

    char* ws = (char*)d_ws;

    // workspace layout
    size_t o_cnt  = 0;                                                  // padded counters, 6.4 MB
    size_t o_row  = alignup(o_cnt + (size_t)N_NODES * CNT_STRIDE * 4);
    size_t o_bsum = alignup(o_row + (size_t)(N_NODES + 1) * 4);
    size_t o_bpre = alignup(o_bsum + (size_t)NBLK * 4);
    size_t o_sp   = alignup(o_bpre + (size_t)NBLK * 4);                 // int2 pairs, 12.8 MB
    size_t o_xA   = alignup(o_sp + (size_t)N_EDGES * 8);
    size_t o_xB   = alignup(o_xA + (size_t)N_NODES * DIM * 4);
    size_t o_msg  = alignup(o_xB + (size_t)N_NODES * DIM * 4);          // 32 MB; rank aliases head
    size_t needed = o_msg + (size_t)N_EDGES * DIM * 4;

    dim3 blk(256);
    dim3 eg((N_EDGES + 255) / 256);
    dim3 ng((N_NODES + 255) / 256);

    if (ws_size < needed) {
        // fallback: atomic scatter path (proven correct)
        size_t nbytes = (size_t)N_NODES * DIM * sizeof(float);
        float* aggr = (float*)ws;
        float* xA   = (float*)(ws + nbytes);
        float* xB   = (float*)(ws + 2 * nbytes);
        const float* xcur = x;
        for (int l = 0; l < N_LAYERS; ++l) {
            hipMemsetAsync(aggr, 0, nbytes, stream);
            edge_msg_kernel<<<eg, blk, 0, stream>>>(
                xcur, ei, W1 + l * 10 * HID, b1 + l * HID,
                W2 + l * HID * DIM, b2 + l * DIM, aggr);
            if (l < N_LAYERS - 1) {
                float* xn = (l == 0) ? xA : xB;
                node_upd_kernel<false><<<ng, blk, 0, stream>>>(
                    xcur, aggr, U1 + l * 10 * HID, bu1 + l * HID,
                    U2 + l * HID * DIM, bu2 + l * DIM, Wr, br, xn);
                xcur = xn;
            } else {
                node_upd_kernel<true><<<ng, blk, 0, stream>>>(
                    xcur, aggr, U1 + l * 10 * HID, bu1 + l * HID,
                    U2 + l * HID * DIM, bu2 + l * DIM, Wr, br, out);
            }
        }
        return;
    }

    int* cnt      = (int*)(ws + o_cnt);
    int* row_ptr  = (int*)(ws + o_row);
    int* blk_sum  = (int*)(ws + o_bsum);
    int* blk_pref = (int*)(ws + o_bpre);
    int2* spair   = (int2*)(ws + o_sp);
    float* xA     = (float*)(ws + o_xA);
    float* xB     = (float*)(ws + o_xB);
    float* msgbuf = (float*)(ws + o_msg);
    int* rank     = (int*)(ws + o_msg);   // aliases msg_buf (build phase only)

    // ---- CSR build (once per call; reused by all 3 layers) ----
    hipMemsetAsync(cnt, 0, (size_t)N_NODES * CNT_STRIDE * 4, stream);
    hist_kernel<<<eg, blk, 0, stream>>>(ei, cnt, rank);
    scan_part_kernel<<<NBLK, SCAN_BLK, 0, stream>>>(cnt, blk_sum);
    scan_blk_kernel<<<1, 512, 0, stream>>>(blk_sum, blk_pref);
    scan_add_kernel<<<NBLK, SCAN_BLK, 0, stream>>>(cnt, blk_pref, row_ptr);
    scatter_pair_kernel<<<eg, blk, 0, stream>>>(ei, rank, row_ptr, spair);

    // ---- layers ----
    const float* xcur = x;
    for (int l = 0; l < N_LAYERS; ++l) {
        edge_msg_sorted_kernel<<<eg, blk, 0, stream>>>(
            xcur, spair, W1 + l * 10 * HID, b1 + l * HID,
            W2 + l * HID * DIM, b2 + l * DIM, msgbuf);
        if (l < N_LAYERS - 1) {
            float* xn = (l == 0) ? xA : xB;
            node_gather_update_kernel<false><<<ng, blk, 0, stream>>>(
                xcur, msgbuf, row_ptr, U1 + l * 10 * HID, bu1 + l * HID,
                U2 + l * HID * DIM, bu2 + l * DIM, Wr, br, xn);
            xcur = xn;
        } else {
            node_gather_update_kernel<true><<<ng, blk, 0, stream>>>(
                xcur, msgbuf, row_ptr, U1 + l * 10 * HID, bu1 + l * HID,
                U2 + l * HID * DIM, bu2 + l * DIM, Wr, br, out);
        }
    }
}

// Round 11
// 386.115 us; speedup vs baseline: 1.7462x; 1.0031x over previous
//
#include <hip/hip_runtime.h>

#define N_NODES 100000
#define N_EDGES 1600000
#define DIM 5
#define HID 64
#define N_LAYERS 3
#define SCAN_BLK 256
#define NBLK ((N_NODES + SCAN_BLK - 1) / SCAN_BLK)   // 391

// ================= CSR build =================

__global__ __launch_bounds__(256) void hist_kernel(
    const int* __restrict__ ei, int* __restrict__ cnt, int* __restrict__ rank)
{
    int e = blockIdx.x * blockDim.x + threadIdx.x;
    if (e >= N_EDGES) return;
    int dst = ei[N_EDGES + e];
    rank[e] = atomicAdd(&cnt[dst], 1);
}

__global__ __launch_bounds__(SCAN_BLK) void scan_part_kernel(
    const int* __restrict__ cnt, int* __restrict__ blk_sum)
{
    __shared__ int s[SCAN_BLK];
    int t = threadIdx.x;
    int i = blockIdx.x * SCAN_BLK + t;
    s[t] = (i < N_NODES) ? cnt[i] : 0;
    __syncthreads();
    for (int off = SCAN_BLK / 2; off > 0; off >>= 1) {
        if (t < off) s[t] += s[t + off];
        __syncthreads();
    }
    if (t == 0) blk_sum[blockIdx.x] = s[0];
}

__global__ __launch_bounds__(512) void scan_blk_kernel(
    const int* __restrict__ blk_sum, int* __restrict__ blk_pref)
{
    __shared__ int s[512];
    int t = threadIdx.x;
    int v = (t < NBLK) ? blk_sum[t] : 0;
    s[t] = v;
    __syncthreads();
    for (int off = 1; off < 512; off <<= 1) {
        int a = (t >= off) ? s[t - off] : 0;
        __syncthreads();
        s[t] += a;
        __syncthreads();
    }
    if (t < NBLK) blk_pref[t] = s[t] - v;   // exclusive prefix
}

__global__ __launch_bounds__(SCAN_BLK) void scan_add_kernel(
    const int* __restrict__ cnt, const int* __restrict__ blk_pref,
    int* __restrict__ row_ptr)
{
    __shared__ int s[SCAN_BLK];
    int t = threadIdx.x;
    int i = blockIdx.x * SCAN_BLK + t;
    int c = (i < N_NODES) ? cnt[i] : 0;
    s[t] = c;
    __syncthreads();
    for (int off = 1; off < SCAN_BLK; off <<= 1) {
        int a = (t >= off) ? s[t - off] : 0;
        __syncthreads();
        s[t] += a;
        __syncthreads();
    }
    if (i < N_NODES) row_ptr[i] = blk_pref[blockIdx.x] + s[t] - c;
    if (i == 0) row_ptr[N_NODES] = N_EDGES;
}

// write one int2 {src,dst} per edge at its sorted position (8B random write)
__global__ __launch_bounds__(256) void scatter_pair_kernel(
    const int* __restrict__ ei, const int* __restrict__ rank,
    const int* __restrict__ row_ptr, int2* __restrict__ spair)
{
    int e = blockIdx.x * blockDim.x + threadIdx.x;
    if (e >= N_EDGES) return;
    int src = ei[e];
    int dst = ei[N_EDGES + e];
    spair[row_ptr[dst] + rank[e]] = make_int2(src, dst);
}

// ================= per-layer kernels (atomic-free) =================

// msg = relu([x_dst, x_src] @ W1 + b1) @ W2 + b2, written at sorted position
__global__ __launch_bounds__(256) void edge_msg_sorted_kernel(
    const float* __restrict__ x,
    const int2* __restrict__ spair,
    const float* __restrict__ W1, const float* __restrict__ b1,
    const float* __restrict__ W2, const float* __restrict__ b2,
    float* __restrict__ msg_buf)
{
    int e = blockIdx.x * blockDim.x + threadIdx.x;
    if (e >= N_EDGES) return;
    int2 p = spair[e];          // p.x = src, p.y = dst

    float in[10];
    const float* xi = x + (long)p.y * DIM;
    const float* xj = x + (long)p.x * DIM;
#pragma unroll
    for (int d = 0; d < DIM; ++d) in[d] = xi[d];
#pragma unroll
    for (int d = 0; d < DIM; ++d) in[DIM + d] = xj[d];

    float msg[DIM];
#pragma unroll
    for (int j = 0; j < DIM; ++j) msg[j] = b2[j];

#pragma unroll 8
    for (int h = 0; h < HID; ++h) {
        float acc = b1[h];
#pragma unroll
        for (int d = 0; d < 10; ++d) acc = fmaf(in[d], W1[d * HID + h], acc);
        acc = fmaxf(acc, 0.0f);
#pragma unroll
        for (int j = 0; j < DIM; ++j) msg[j] = fmaf(acc, W2[h * DIM + j], msg[j]);
    }

    float* mp = msg_buf + (long)e * DIM;
#pragma unroll
    for (int j = 0; j < DIM; ++j) mp[j] = msg[j];
}

// 8 lanes per node: lanes split the msg-segment sum and the 64 h-units of the
// update MLP; __shfl_xor butterflies (masks 1,2,4 stay within the 8-lane group)
// reduce agg[5] and upd[5]. Lane 0 writes (residual / readout).
template <bool FINAL>
__global__ __launch_bounds__(256) void gather_update8_kernel(
    const float* __restrict__ x,
    const float* __restrict__ msg_buf,
    const int* __restrict__ row_ptr,
    const float* __restrict__ U1, const float* __restrict__ bu1,
    const float* __restrict__ U2, const float* __restrict__ bu2,
    const float* __restrict__ Wr, const float* __restrict__ br,
    float* __restrict__ xout)
{
    int gt = blockIdx.x * blockDim.x + threadIdx.x;   // 800000 threads exactly
    int v = gt >> 3;
    int r = gt & 7;
    if (v >= N_NODES) return;

    int s = row_ptr[v], e1 = row_ptr[v + 1];

    // strided segment sum: lane r takes edges s+r, s+r+8, ...
    float agg[DIM] = {0.f, 0.f, 0.f, 0.f, 0.f};
    for (int e = s + r; e < e1; e += 8) {
        const float* mp = msg_buf + (long)e * DIM;
#pragma unroll
        for (int j = 0; j < DIM; ++j) agg[j] += mp[j];
    }
#pragma unroll
    for (int m = 1; m < 8; m <<= 1) {
#pragma unroll
        for (int j = 0; j < DIM; ++j) agg[j] += __shfl_xor(agg[j], m, 64);
    }

    float in2[10];
#pragma unroll
    for (int d = 0; d < DIM; ++d) in2[d] = x[(long)v * DIM + d];
#pragma unroll
    for (int d = 0; d < DIM; ++d) in2[DIM + d] = agg[d];

    // lane r computes h = r, r+8, ..., r+56  (U1 column reads coalesced)
    float upd[DIM] = {0.f, 0.f, 0.f, 0.f, 0.f};
#pragma unroll
    for (int hh = 0; hh < 8; ++hh) {
        int h = r + hh * 8;
        float acc = bu1[h];
#pragma unroll
        for (int d = 0; d < 10; ++d) acc = fmaf(in2[d], U1[d * HID + h], acc);
        acc = fmaxf(acc, 0.0f);
#pragma unroll
        for (int j = 0; j < DIM; ++j) upd[j] = fmaf(acc, U2[h * DIM + j], upd[j]);
    }
#pragma unroll
    for (int m = 1; m < 8; m <<= 1) {
#pragma unroll
        for (int j = 0; j < DIM; ++j) upd[j] += __shfl_xor(upd[j], m, 64);
    }

    if (r == 0) {
        float xn[DIM];
#pragma unroll
        for (int j = 0; j < DIM; ++j) xn[j] = upd[j] + bu2[j] + in2[j];
        if (FINAL) {
#pragma unroll
            for (int j = 0; j < DIM; ++j) {
                float o = br[j];
#pragma unroll
                for (int d = 0; d < DIM; ++d) o = fmaf(xn[d], Wr[d * DIM + j], o);
                xout[(long)v * DIM + j] = o;
            }
        } else {
#pragma unroll
            for (int j = 0; j < DIM; ++j) xout[(long)v * DIM + j] = xn[j];
        }
    }
}

// ================= fallback (round-3 atomic path) =================

__global__ __launch_bounds__(256) void edge_msg_kernel(
    const float* __restrict__ x, const int* __restrict__ ei,
    const float* __restrict__ W1, const float* __restrict__ b1,
    const float* __restrict__ W2, const float* __restrict__ b2,
    float* __restrict__ aggr)
{
    int e = blockIdx.x * blockDim.x + threadIdx.x;
    if (e >= N_EDGES) return;
    int src = ei[e];
    int dst = ei[N_EDGES + e];
    float in[10];
    const float* xi = x + (long)dst * DIM;
    const float* xj = x + (long)src * DIM;
#pragma unroll
    for (int d = 0; d < DIM; ++d) in[d] = xi[d];
#pragma unroll
    for (int d = 0; d < DIM; ++d) in[DIM + d] = xj[d];
    float msg[DIM];
#pragma unroll
    for (int j = 0; j < DIM; ++j) msg[j] = b2[j];
#pragma unroll 8
    for (int h = 0; h < HID; ++h) {
        float acc = b1[h];
#pragma unroll
        for (int d = 0; d < 10; ++d) acc = fmaf(in[d], W1[d * HID + h], acc);
        acc = fmaxf(acc, 0.0f);
#pragma unroll
        for (int j = 0; j < DIM; ++j) msg[j] = fmaf(acc, W2[h * DIM + j], msg[j]);
    }
    float* ap = aggr + (long)dst * DIM;
#pragma unroll
    for (int j = 0; j < DIM; ++j) atomicAdd(ap + j, msg[j]);
}

template <bool FINAL>
__global__ __launch_bounds__(256) void node_upd_kernel(
    const float* __restrict__ x, const float* __restrict__ aggr,
    const float* __restrict__ U1, const float* __restrict__ bu1,
    const float* __restrict__ U2, const float* __restrict__ bu2,
    const float* __restrict__ Wr, const float* __restrict__ br,
    float* __restrict__ xout)
{
    int v = blockIdx.x * blockDim.x + threadIdx.x;
    if (v >= N_NODES) return;
    float in[10];
#pragma unroll
    for (int d = 0; d < DIM; ++d) in[d] = x[(long)v * DIM + d];
#pragma unroll
    for (int d = 0; d < DIM; ++d) in[DIM + d] = aggr[(long)v * DIM + d];
    float upd[DIM];
#pragma unroll
    for (int j = 0; j < DIM; ++j) upd[j] = bu2[j];
#pragma unroll 8
    for (int h = 0; h < HID; ++h) {
        float acc = bu1[h];
#pragma unroll
        for (int d = 0; d < 10; ++d) acc = fmaf(in[d], U1[d * HID + h], acc);
        acc = fmaxf(acc, 0.0f);
#pragma unroll
        for (int j = 0; j < DIM; ++j) upd[j] = fmaf(acc, U2[h * DIM + j], upd[j]);
    }
    float xn[DIM];
#pragma unroll
    for (int j = 0; j < DIM; ++j) xn[j] = upd[j] + in[j];
    if (FINAL) {
#pragma unroll
        for (int j = 0; j < DIM; ++j) {
            float o = br[j];
#pragma unroll
            for (int d = 0; d < DIM; ++d) o = fmaf(xn[d], Wr[d * DIM + j], o);
            xout[(long)v * DIM + j] = o;
        }
    } else {
#pragma unroll
        for (int j = 0; j < DIM; ++j) xout[(long)v * DIM + j] = xn[j];
    }
}

// ================= launch =================

static inline size_t alignup(size_t x) { return (x + 255) & ~(size_t)255; }

extern "C" void kernel_launch(void* const* d_in, const int* in_sizes, int n_in,
                              void* d_out, int out_size, void* d_ws, size_t ws_size,
                              hipStream_t stream) {
    const float* x   = (const float*)d_in[0];
    const int*   ei  = (const int*)d_in[1];
    const float* W1  = (const float*)d_in[2];
    const float* b1  = (const float*)d_in[3];
    const float* W2  = (const float*)d_in[4];
    const float* b2  = (const float*)d_in[5];
    const float* U1  = (const float*)d_in[6];
    const float* bu1 = (const float*)d_in[7];
    const float* U2  = (const float*)d_in[8];
    const float* bu2 = (const float*)d_in[9];
    const float* Wr  = (const float*)d_in[10];
    const float* br  = (const float*)d_in[11];
    float* out = (float*)d_out;

    char* ws = (char*)d_ws;

    // workspace layout (cnt un-padded: padding probe was NULL)
    size_t o_cnt  = 0;
    size_t o_row  = alignup(o_cnt + (size_t)N_NODES * 4);
    size_t o_bsum = alignup(o_row + (size_t)(N_NODES + 1) * 4);
    size_t o_bpre = alignup(o_bsum + (size_t)NBLK * 4);
    size_t o_sp   = alignup(o_bpre + (size_t)NBLK * 4);                 // int2 pairs, 12.8 MB
    size_t o_xA   = alignup(o_sp + (size_t)N_EDGES * 8);
    size_t o_xB   = alignup(o_xA + (size_t)N_NODES * DIM * 4);
    size_t o_msg  = alignup(o_xB + (size_t)N_NODES * DIM * 4);          // 32 MB; rank aliases head
    size_t needed = o_msg + (size_t)N_EDGES * DIM * 4;

    dim3 blk(256);
    dim3 eg((N_EDGES + 255) / 256);
    dim3 ng((N_NODES + 255) / 256);
    dim3 ng8((N_NODES * 8 + 255) / 256);   // 3125 blocks, exact

    if (ws_size < needed) {
        // fallback: atomic scatter path (proven correct)
        size_t nbytes = (size_t)N_NODES * DIM * sizeof(float);
        float* aggr = (float*)ws;
        float* xA   = (float*)(ws + nbytes);
        float* xB   = (float*)(ws + 2 * nbytes);
        const float* xcur = x;
        for (int l = 0; l < N_LAYERS; ++l) {
            hipMemsetAsync(aggr, 0, nbytes, stream);
            edge_msg_kernel<<<eg, blk, 0, stream>>>(
                xcur, ei, W1 + l * 10 * HID, b1 + l * HID,
                W2 + l * HID * DIM, b2 + l * DIM, aggr);
            if (l < N_LAYERS - 1) {
                float* xn = (l == 0) ? xA : xB;
                node_upd_kernel<false><<<ng, blk, 0, stream>>>(
                    xcur, aggr, U1 + l * 10 * HID, bu1 + l * HID,
                    U2 + l * HID * DIM, bu2 + l * DIM, Wr, br, xn);
                xcur = xn;
            } else {
                node_upd_kernel<true><<<ng, blk, 0, stream>>>(
                    xcur, aggr, U1 + l * 10 * HID, bu1 + l * HID,
                    U2 + l * HID * DIM, bu2 + l * DIM, Wr, br, out);
            }
        }
        return;
    }

    int* cnt      = (int*)(ws + o_cnt);
    int* row_ptr  = (int*)(ws + o_row);
    int* blk_sum  = (int*)(ws + o_bsum);
    int* blk_pref = (int*)(ws + o_bpre);
    int2* spair   = (int2*)(ws + o_sp);
    float* xA     = (float*)(ws + o_xA);
    float* xB     = (float*)(ws + o_xB);
    float* msgbuf = (float*)(ws + o_msg);
    int* rank     = (int*)(ws + o_msg);   // aliases msg_buf (build phase only)

    // ---- CSR build (once per call; reused by all 3 layers) ----
    hipMemsetAsync(cnt, 0, (size_t)N_NODES * 4, stream);
    hist_kernel<<<eg, blk, 0, stream>>>(ei, cnt, rank);
    scan_part_kernel<<<NBLK, SCAN_BLK, 0, stream>>>(cnt, blk_sum);
    scan_blk_kernel<<<1, 512, 0, stream>>>(blk_sum, blk_pref);
    scan_add_kernel<<<NBLK, SCAN_BLK, 0, stream>>>(cnt, blk_pref, row_ptr);
    scatter_pair_kernel<<<eg, blk, 0, stream>>>(ei, rank, row_ptr, spair);

    // ---- layers ----
    const float* xcur = x;
    for (int l = 0; l < N_LAYERS; ++l) {
        edge_msg_sorted_kernel<<<eg, blk, 0, stream>>>(
            xcur, spair, W1 + l * 10 * HID, b1 + l * HID,
            W2 + l * HID * DIM, b2 + l * DIM, msgbuf);
        if (l < N_LAYERS - 1) {
            float* xn = (l == 0) ? xA : xB;
            gather_update8_kernel<false><<<ng8, blk, 0, stream>>>(
                xcur, msgbuf, row_ptr, U1 + l * 10 * HID, bu1 + l * HID,
                U2 + l * HID * DIM, bu2 + l * DIM, Wr, br, xn);
            xcur = xn;
        } else {
            gather_update8_kernel<true><<<ng8, blk, 0, stream>>>(
                xcur, msgbuf, row_ptr, U1 + l * 10 * HID, bu1 + l * HID,
                U2 + l * HID * DIM, bu2 + l * DIM, Wr, br, out);
        }
    }
}